// Round 4
// baseline (96.396 us; speedup 1.0000x reference)
//
#include <hip/hip_runtime.h>
#include <math.h>

#define L_TOT   589      // int(round(fp32(49*1.2f)/0.1))+1
#define NDELAY  30       // int(3/0.1) == 30
#define NSAMP   50
#define HW_PIX  102400   // 320*320
#define STEPF   0.1f
#define BLK     256

// One kernel, no d_ws. Each block rebuilds the shared AIF + sample indices in
// LDS, then one thread per pixel runs two exponential-convolution recurrences
// (FFT conv of a 2-exp impulse response == S_n = r*S_{n-1} + aif[n]).
// Hot loop is a two-level structure: outer over the 50 samples with
// wave-uniform SGPR bounds (readfirstlane), inner a tight 2-FMA recurrence.
// No dynamically-indexed private arrays (scratch-spill hazard), no divergent
// branch in the inner loop.
__global__ __launch_bounds__(BLK) void dce_kernel(
    const float* __restrict__ param,
    const float* __restrict__ st_g,
    const float* __restrict__ cp_g,
    float* __restrict__ out,          // fp32 output
    float M0_trans, float cos_fa, float sig_base)
{
    __shared__ float s_aif[L_TOT];
    __shared__ float s_st[NSAMP], s_cp[NSAMP];
    __shared__ int   s_idx[NSAMP];

    const int tid = threadIdx.x;
    if (tid < NSAMP) { s_st[tid] = st_g[tid]; s_cp[tid] = cp_g[tid]; }
    __syncthreads();

    // AIF: linear interp of Cp onto the 0.1s grid, delayed NDELAY steps.
    for (int k = tid; k < L_TOT; k += BLK) {
        float v = 0.0f;
        if (k >= NDELAY) {
            float t = (float)(k - NDELAY) * STEPF;   // == t_samp[k-30] bitwise
            int j = (k - NDELAY) / 12;               // st spacing 1.2 s = 12 steps
            if (j > NSAMP - 2) j = NSAMP - 2;
            if (s_st[j + 1] <= t) ++j;               // exact-fp32 boundary fixups
            if (j > 0 && s_st[j] > t) --j;
            v = s_cp[j] + (t - s_st[j]) * (s_cp[j + 1] - s_cp[j])
                        / (s_st[j + 1] - s_st[j]);
        }
        s_aif[k] = v;
    }
    // searchsorted(t_samp, sample_time, 'left') via 5-wide exact-fp32 window;
    // JAX gather clamps OOB (last idx 589 -> 588).
    if (tid < NSAMP) {
        float sv = s_st[tid];
        int lo = 12 * tid - 2; if (lo < 0) lo = 0;
        int cnt = lo;
        for (int n = lo; n <= 12 * tid + 2; ++n)
            if ((float)n * STEPF < sv) cnt = n + 1;   // monotone predicate
        s_idx[tid] = min(cnt, L_TOT - 1);
    }
    __syncthreads();

    const int pix = blockIdx.x * BLK + tid;
    const float ve = param[0 * HW_PIX + pix];
    const float vp = param[1 * HW_PIX + pix];
    const float fp = param[2 * HW_PIX + pix];
    const float ps = param[3 * HW_PIX + pix];

    // params in [0.05,1] => all quantities finite/positive; _nan0 never fires
    const float Te = ve / ps;
    const float T  = (vp + ve) / fp;
    const float Tc = vp / fp;
    const float sm = T + Te;
    const float disc = sqrtf(sm * sm - 4.0f * Tc * Te);
    const float den2 = 2.0f * Tc * Te;
    const float thp = (sm + disc) / den2;
    const float thm = (sm - disc) / den2;

    const float rm = expf(-STEPF * thm);
    const float rp = expf(-STEPF * thp);

    // normalizers: geometric sums over the 589-point grid.
    // thm >= 1/60 -> 1-rm >= 1.6e-3: no catastrophic cancellation.
    const float Se = (1.0f - expf(-(STEPF * (float)L_TOT) * thm)) / (1.0f - rm);
    const float Sp = (1.0f - expf(-(STEPF * (float)L_TOT) * thp)) / (1.0f - rp);

    const float we  = 1.0f - Te * thm;   // > 0 (Te*thm < 1)
    const float wpp = Te * thp - 1.0f;   // > 0 (Te*thp > 1)
    const float inv_De = 1.0f / (Se - Sp);             // Se > Sp strictly
    const float inv_Dp = 1.0f / (we * Se + wpp * Sp);  // > 0 strictly

    float Sm = 0.0f, Spv = 0.0f;
    int cur = 0;

    #pragma unroll 1
    for (int s = 0; s < NSAMP; ++s) {
        // wave-uniform sample index -> SGPR loop bound, zero divergence
        const int t = __builtin_amdgcn_readfirstlane(s_idx[s]);
        for (int n = cur; n <= t; ++n) {
            const float a = s_aif[n];
            Sm  = fmaf(Sm,  rm, a);
            Spv = fmaf(Spv, rp, a);
        }
        cur = t + 1;

        const float ce   = (Sm - Spv) * inv_De;
        const float cpv  = (we * Sm + wpp * Spv) * inv_Dp;
        const float conc = vp * cpv + ve * ce;
        const float E1CA = expf(-0.00487f * fmaf(4.3f, conc, 1.0f));
        const float catr = M0_trans * (1.0f - E1CA) / (1.0f - E1CA * cos_fa);
        out[s * HW_PIX + pix] = catr + sig_base;
    }
}

extern "C" void kernel_launch(void* const* d_in, const int* in_sizes, int n_in,
                              void* d_out, int out_size, void* d_ws, size_t ws_size,
                              hipStream_t stream) {
    const float* param = (const float*)d_in[0];
    const float* st    = (const float*)d_in[1];
    const float* Cp    = (const float*)d_in[2];
    float* out = (float*)d_out;

    // signal-equation constants (host double, then cast)
    double fa   = 10.0 * M_PI / 180.0;
    double cfa  = cos(fa), sfa = sin(fa);
    double E1   = exp(-0.00487);
    double M0   = 100.0 * (1.0 - cfa * E1) / (sfa * (1.0 - E1));
    double M0t  = M0 * sfa;
    double Mst  = M0t * (1.0 - E1) / (1.0 - E1 * cfa);
    float M0_trans = (float)M0t;
    float cos_fa   = (float)cfa;
    float sig_base = (float)(100.0 - Mst);

    dce_kernel<<<HW_PIX / BLK, BLK, 0, stream>>>(param, st, Cp, out,
                                                 M0_trans, cos_fa, sig_base);
}

// Round 5
// 85.956 us; speedup vs baseline: 1.1215x; 1.1215x over previous
//
#include <hip/hip_runtime.h>
#include <math.h>

#define L_TOT   589      // int(round(fp32(49*1.2f)/0.1))+1
#define L_PAD   592      // pad to 8-multiple; pad steps run with aif=0 AFTER last sample
#define NCHUNK  (L_PAD / 8)   // 74
#define NDELAY  30
#define NSAMP   50
#define HW_PIX  102400   // 320*320
#define STEPF   0.1f
#define BLK     64

// One kernel, no d_ws. Per block: rebuild shared AIF + sample indices in LDS,
// then one thread per pixel runs two exponential-convolution recurrences
// (FFT conv of 2-exp impulse response == S_n = r*S_{n-1} + aif[n]).
// Hot loop: 74 fixed chunks of 8 steps, two float4 LDS reads per chunk with
// register double-buffering (prefetch q+1 while computing q) so LDS latency
// hides behind 16 FMAs. Emission check is a wave-uniform scalar compare.
__global__ __launch_bounds__(BLK) void dce_kernel(
    const float* __restrict__ param,
    const float* __restrict__ st_g,
    const float* __restrict__ cp_g,
    float* __restrict__ out,          // fp32 output
    float M0_trans, float cos_fa, float sig_base)
{
    __shared__ __align__(16) float s_aif[L_PAD];
    __shared__ float s_st[NSAMP], s_cp[NSAMP];
    __shared__ int   s_idx[NSAMP];

    const int tid = threadIdx.x;
    if (tid < NSAMP) { s_st[tid] = st_g[tid]; s_cp[tid] = cp_g[tid]; }
    __syncthreads();

    // AIF: linear interp of Cp onto 0.1s grid, delayed NDELAY steps. Pad = 0.
    for (int k = tid; k < L_PAD; k += BLK) {
        float v = 0.0f;
        if (k >= NDELAY && k < L_TOT) {
            float t = (float)(k - NDELAY) * STEPF;   // == t_samp[k-30] bitwise
            int j = (k - NDELAY) / 12;               // st spacing 1.2 s = 12 steps
            if (j > NSAMP - 2) j = NSAMP - 2;
            if (s_st[j + 1] <= t) ++j;               // exact-fp32 boundary fixups
            if (j > 0 && s_st[j] > t) --j;
            v = s_cp[j] + (t - s_st[j]) * (s_cp[j + 1] - s_cp[j])
                        / (s_st[j + 1] - s_st[j]);
        }
        s_aif[k] = v;
    }
    // searchsorted(t_samp, sample_time, 'left'), exact fp32, clamped like gather
    if (tid < NSAMP) {
        float sv = s_st[tid];
        int lo = 12 * tid - 2; if (lo < 0) lo = 0;
        int cnt = lo;
        for (int n = lo; n <= 12 * tid + 2; ++n)
            if ((float)n * STEPF < sv) cnt = n + 1;   // monotone predicate
        s_idx[tid] = min(cnt, L_TOT - 1);
    }
    __syncthreads();

    const int pix = blockIdx.x * BLK + tid;
    const float ve = param[0 * HW_PIX + pix];
    const float vp = param[1 * HW_PIX + pix];
    const float fp = param[2 * HW_PIX + pix];
    const float ps = param[3 * HW_PIX + pix];

    // params in [0.05,1] => all finite/positive; reference _nan0 never fires
    const float Te = ve / ps;
    const float T  = (vp + ve) / fp;
    const float Tc = vp / fp;
    const float sm = T + Te;
    const float disc = sqrtf(sm * sm - 4.0f * Tc * Te);
    const float den2 = 2.0f * Tc * Te;
    const float thp = (sm + disc) / den2;
    const float thm = (sm - disc) / den2;

    const float rm = expf(-STEPF * thm);
    const float rp = expf(-STEPF * thp);

    // normalizers: geometric sums over the 589-point grid (1-rm >= 1.6e-3)
    const float Se = (1.0f - expf(-(STEPF * (float)L_TOT) * thm)) / (1.0f - rm);
    const float Sp = (1.0f - expf(-(STEPF * (float)L_TOT) * thp)) / (1.0f - rp);

    const float we  = 1.0f - Te * thm;   // > 0
    const float wpp = Te * thp - 1.0f;   // > 0
    const float inv_De = 1.0f / (Se - Sp);             // Se > Sp strictly
    const float inv_Dp = 1.0f / (we * Se + wpp * Sp);  // > 0 strictly

    float Sm = 0.0f, Spv = 0.0f;
    int s = 0;
    int next = __builtin_amdgcn_readfirstlane(s_idx[0]);

    const float4* aif4 = (const float4*)s_aif;
    float4 ca = aif4[0], cb = aif4[1];   // current chunk (8 steps)

    #pragma unroll 1
    for (int q = 0; q < NCHUNK; ++q) {
        // prefetch next chunk; compiler leaves these in flight (lgkmcnt>0)
        float4 na = ca, nb = cb;
        if (q + 1 < NCHUNK) { na = aif4[2 * q + 2]; nb = aif4[2 * q + 3]; }
        const int base = q * 8;

#define DCE_STEP(A, U)                                                        \
        { const float a_ = (A);                                               \
          Sm  = fmaf(Sm,  rm, a_);                                            \
          Spv = fmaf(Spv, rp, a_);                                            \
          if (base + (U) == next) {      /* uniform: scalar branch */         \
              const float ce_   = (Sm - Spv) * inv_De;                        \
              const float cpv_  = (we * Sm + wpp * Spv) * inv_Dp;             \
              const float conc_ = vp * cpv_ + ve * ce_;                       \
              const float E1CA_ = __expf(-0.00487f * fmaf(4.3f, conc_, 1.0f));\
              const float catr_ = M0_trans * (1.0f - E1CA_)                   \
                                / (1.0f - E1CA_ * cos_fa);                    \
              out[s * HW_PIX + pix] = catr_ + sig_base;                       \
              ++s;                                                            \
              next = (s < NSAMP) ? __builtin_amdgcn_readfirstlane(s_idx[s])   \
                                 : -1;                                        \
          } }

        DCE_STEP(ca.x, 0) DCE_STEP(ca.y, 1) DCE_STEP(ca.z, 2) DCE_STEP(ca.w, 3)
        DCE_STEP(cb.x, 4) DCE_STEP(cb.y, 5) DCE_STEP(cb.z, 6) DCE_STEP(cb.w, 7)
#undef DCE_STEP
        ca = na; cb = nb;
    }
}

extern "C" void kernel_launch(void* const* d_in, const int* in_sizes, int n_in,
                              void* d_out, int out_size, void* d_ws, size_t ws_size,
                              hipStream_t stream) {
    const float* param = (const float*)d_in[0];
    const float* st    = (const float*)d_in[1];
    const float* Cp    = (const float*)d_in[2];
    float* out = (float*)d_out;

    // signal-equation constants (host double, then cast)
    double fa   = 10.0 * M_PI / 180.0;
    double cfa  = cos(fa), sfa = sin(fa);
    double E1   = exp(-0.00487);
    double M0   = 100.0 * (1.0 - cfa * E1) / (sfa * (1.0 - E1));
    double M0t  = M0 * sfa;
    double Mst  = M0t * (1.0 - E1) / (1.0 - E1 * cfa);
    float M0_trans = (float)M0t;
    float cos_fa   = (float)cfa;
    float sig_base = (float)(100.0 - Mst);

    dce_kernel<<<HW_PIX / BLK, BLK, 0, stream>>>(param, st, Cp, out,
                                                 M0_trans, cos_fa, sig_base);
}